// Round 12
// baseline (215.578 us; speedup 1.0000x reference)
//
#include <hip/hip_runtime.h>
#include <hip/hip_bf16.h>

#define Bb 4
#define Ss 2048
#define Ee 512
#define Hh 8
#define DKk 64
// M = Bb*Ss = 8192

typedef __bf16 bf16_t;
typedef bf16_t bf16x8 __attribute__((ext_vector_type(8)));
typedef bf16_t bf16x4 __attribute__((ext_vector_type(4)));
typedef float f32x4 __attribute__((ext_vector_type(4)));
typedef float f32x16 __attribute__((ext_vector_type(16)));

#define MFMA16(a, b, c) __builtin_amdgcn_mfma_f32_16x16x32_bf16(a, b, c, 0, 0, 0)
#define MFMA32(a, b, c) __builtin_amdgcn_mfma_f32_32x32x16_bf16(a, b, c, 0, 0, 0)

#define GLOAD16(src, dst)                                          \
  __builtin_amdgcn_global_load_lds(                                \
      (const __attribute__((address_space(1))) void*)(src),        \
      (__attribute__((address_space(3))) void*)(dst), 16, 0, 0)

#define LO4(v) __builtin_shufflevector(v, v, 0, 1, 2, 3)
#define HI4(v) __builtin_shufflevector(v, v, 4, 5, 6, 7)

static __device__ __forceinline__ bf16_t f2bf(float f) { return (bf16_t)f; }

static __device__ __forceinline__ float fast_exp2(float x) {
#if __has_builtin(__builtin_amdgcn_exp2f)
  return __builtin_amdgcn_exp2f(x);
#else
  return exp2f(x);
#endif
}

static __device__ __forceinline__ float max3f(float a, float b, float c) {
  return fmaxf(fmaxf(a, b), c);  // clang fuses to v_max3_f32
}

static __device__ __forceinline__ unsigned cvtpk(float lo, float hi) {
  unsigned r;
  asm("v_cvt_pk_bf16_f32 %0, %1, %2" : "=v"(r) : "v"(lo), "v"(hi));
  return r;
}
// v_permlane32_swap_b32: A[32:63] <-> B[0:31].
static __device__ __forceinline__ void plswap(unsigned& a, unsigned& b) {
  asm("v_permlane32_swap_b32 %0, %1" : "+v"(a), "+v"(b));
}

// ---------------------------------------------------------------------------
// Pack: transpose + fp32->bf16 weights.
//  Wt[mat][n = h*64+d][k = e] = W_mat[h][e][d]   (mat = 0,1,2 : Wq,Wk,Wv)
//  Wft[f][e] = Wf[e][f]
// ---------------------------------------------------------------------------
__global__ __launch_bounds__(256) void pack_weights_k(
    const float* __restrict__ Wq, const float* __restrict__ Wk,
    const float* __restrict__ Wv, const float* __restrict__ Wf,
    bf16_t* __restrict__ Wt, bf16_t* __restrict__ Wft) {
  __shared__ float tile[64][65];
  int t = threadIdx.x;
  int y = blockIdx.y;
  const float* sp;
  bf16_t* dp;
  int sR, r0, c0;
  if (y < 24) {
    int mat = y >> 3, h = y & 7;
    const float* W = (mat == 0) ? Wq : ((mat == 1) ? Wk : Wv);
    sp = W + (size_t)h * (Ee * DKk);
    sR = 64;
    dp = Wt + (size_t)mat * (Ee * Ee) + (size_t)(h * 64) * Ee;
    r0 = blockIdx.x * 64;
    c0 = 0;
  } else {
    sp = Wf;
    sR = 512;
    dp = Wft;
    r0 = blockIdx.x * 64;
    c0 = (y - 24) * 64;
  }
  int lr = t >> 2, seg = t & 3;
  const float* sprow = sp + (size_t)(r0 + lr) * sR + c0 + seg * 16;
  float4 f0 = ((const float4*)sprow)[0];
  float4 f1 = ((const float4*)sprow)[1];
  float4 f2 = ((const float4*)sprow)[2];
  float4 f3 = ((const float4*)sprow)[3];
  tile[lr][seg * 16 + 0] = f0.x;  tile[lr][seg * 16 + 1] = f0.y;
  tile[lr][seg * 16 + 2] = f0.z;  tile[lr][seg * 16 + 3] = f0.w;
  tile[lr][seg * 16 + 4] = f1.x;  tile[lr][seg * 16 + 5] = f1.y;
  tile[lr][seg * 16 + 6] = f1.z;  tile[lr][seg * 16 + 7] = f1.w;
  tile[lr][seg * 16 + 8] = f2.x;  tile[lr][seg * 16 + 9] = f2.y;
  tile[lr][seg * 16 + 10] = f2.z; tile[lr][seg * 16 + 11] = f2.w;
  tile[lr][seg * 16 + 12] = f3.x; tile[lr][seg * 16 + 13] = f3.y;
  tile[lr][seg * 16 + 14] = f3.z; tile[lr][seg * 16 + 15] = f3.w;
  __syncthreads();
  bf16x8 o0, o1;
#pragma unroll
  for (int i = 0; i < 8; i++) {
    o0[i] = f2bf(tile[seg * 16 + i][lr]);
    o1[i] = f2bf(tile[seg * 16 + 8 + i][lr]);
  }
  bf16_t* dst = dp + (size_t)(c0 + lr) * Ee + r0 + seg * 16;
  *(bf16x8*)dst = o0;
  *(bf16x8*)(dst + 8) = o1;
}

// ---------------------------------------------------------------------------
// Projection GEMM (operand-swapped): D[n][m] = sum_e Wt[n][e] * X[m][e]
// X is fp32 (raw input), reg-staged + cvt into LDS; W via global_load_lds.
// 64n x 64m tile, BK=64, 4 waves (wn,wm in {0,1}), XOR-chunk swizzle.
// zb 0/1: write q/k [bh][s][dk] bf16 (+scale for q). zb 2: write vtG[bh][dk][s].
// grid (8, 128, 3), 256 threads.
// ---------------------------------------------------------------------------
__global__ __launch_bounds__(256) void proj_gemm_k(
    const float* __restrict__ Qi, const float* __restrict__ Ki,
    const float* __restrict__ Vi, const bf16_t* __restrict__ Wt,
    const float* __restrict__ bq, const float* __restrict__ bk,
    const float* __restrict__ bv, bf16_t* __restrict__ qk,
    bf16_t* __restrict__ vtG) {
  __shared__ bf16_t As[64 * 64];
  __shared__ bf16_t Bs[64 * 64];
  const int t = threadIdx.x;
  const int zb = blockIdx.z;
  const bf16_t* Ap = Wt + (size_t)zb * (Ee * Ee);
  const float* Bp = (zb == 0) ? Qi : ((zb == 1) ? Ki : Vi);
  const float* bias = (zb == 0) ? bq : ((zb == 1) ? bk : bv);
  const float scl = (zb == 0) ? 0.18033688f : 1.0f;  // 0.125 * log2(e) for q
  // T1: bijective XCD-chunk swizzle over 1024 tiles (1024 % 8 == 0)
  const int id = blockIdx.x + (blockIdx.y << 3);
  const int nid = (id & 7) * 128 + (id >> 3);
  const int n0 = (nid & 7) * 64;
  const int m0 = (nid >> 3) * 64;
  const int lane = t & 63, w = t >> 6;
  const int wn = w >> 1, wm = w & 1;
  const int rsel = lane & 15, grp = lane >> 4;
  const int wbase = (t & ~63);

  f32x4 acc[2][2];
#pragma unroll
  for (int ni = 0; ni < 2; ni++)
#pragma unroll
    for (int mi = 0; mi < 2; mi++) acc[ni][mi] = (f32x4){0.f, 0.f, 0.f, 0.f};

  const int row2 = t >> 3, j2 = t & 7;  // B staging role (one 8-elem chunk x2)
  for (int k0 = 0; k0 < Ee; k0 += 64) {
    // A (weights, bf16): global_load_lds, 2 chunks/thread
#pragma unroll
    for (int i = 0; i < 2; i++) {
      int slot = i * 256 + t;
      int row = slot >> 3;
      int g = (slot & 7) ^ (row & 7);
      GLOAD16(Ap + (size_t)(n0 + row) * Ee + k0 + g * 8,
              As + (size_t)(i * 256 + wbase) * 8);
    }
    // B (tokens, fp32 -> bf16): reg-stage + ds_write, 2 chunks/thread
#pragma unroll
    for (int i = 0; i < 2; i++) {
      int row = row2 + i * 32;
      int g = j2 ^ (row & 7);
      const float* src = Bp + (size_t)(m0 + row) * Ee + k0 + g * 8;
      float4 fa = ((const float4*)src)[0];
      float4 fb = ((const float4*)src)[1];
      union { unsigned u[4]; bf16x8 v; } P;
      P.u[0] = cvtpk(fa.x, fa.y); P.u[1] = cvtpk(fa.z, fa.w);
      P.u[2] = cvtpk(fb.x, fb.y); P.u[3] = cvtpk(fb.z, fb.w);
      *(bf16x8*)&Bs[(row * 8 + j2) * 8] = P.v;
    }
    __syncthreads();
#pragma unroll
    for (int kk = 0; kk < 2; kk++) {
      bf16x8 af[2], bff[2];
#pragma unroll
      for (int ni = 0; ni < 2; ni++) {
        int arow = wn * 32 + ni * 16 + rsel;
        int c = ((kk * 4 + grp) ^ (arow & 7)) * 8;
        af[ni] = *(const bf16x8*)&As[arow * 64 + c];
      }
#pragma unroll
      for (int mi = 0; mi < 2; mi++) {
        int brow = wm * 32 + mi * 16 + rsel;
        int c = ((kk * 4 + grp) ^ (brow & 7)) * 8;
        bff[mi] = *(const bf16x8*)&Bs[brow * 64 + c];
      }
#pragma unroll
      for (int ni = 0; ni < 2; ni++)
#pragma unroll
        for (int mi = 0; mi < 2; mi++)
          acc[ni][mi] = MFMA16(af[ni], bff[mi], acc[ni][mi]);
    }
    __syncthreads();
  }

  if (zb < 2) {
    bf16_t* Outp = qk + (size_t)zb * ((size_t)Bb * Hh * Ss * DKk);
#pragma unroll
    for (int ni = 0; ni < 2; ni++) {
      int nb = n0 + wn * 32 + ni * 16 + grp * 4;
      float4 b4 = *(const float4*)(bias + nb);
      const float* b4p = (const float*)&b4;
      int hh = nb >> 6, dd = nb & 63;
#pragma unroll
      for (int mi = 0; mi < 2; mi++) {
        int m = m0 + wm * 32 + mi * 16 + rsel;
        int bI = m >> 11, sI = m & 2047;
        bf16x4 o;
#pragma unroll
        for (int r = 0; r < 4; r++)
          o[r] = f2bf((acc[ni][mi][r] + b4p[r]) * scl);
        *(bf16x4*)(Outp + (((size_t)(bI * Hh + hh)) * Ss + sI) * DKk + dd) = o;
      }
    }
  } else {
    // V: write transposed directly: vtG[(bI*8+hh)*64 + dk][sI]
#pragma unroll
    for (int ni = 0; ni < 2; ni++) {
      int nb = n0 + wn * 32 + ni * 16 + grp * 4;
      float4 b4 = *(const float4*)(bias + nb);
      const float* b4p = (const float*)&b4;
      int hh = nb >> 6, dd = nb & 63;
#pragma unroll
      for (int mi = 0; mi < 2; mi++) {
        int m = m0 + wm * 32 + mi * 16 + rsel;
        int bI = m >> 11, sI = m & 2047;
        bf16_t* base = vtG + (((size_t)(bI * Hh + hh)) * 64 + dd) * Ss + sI;
#pragma unroll
        for (int r = 0; r < 4; r++)
          base[(size_t)r * Ss] = f2bf(acc[ni][mi][r] + b4p[r]);
      }
    }
  }
}

// ---------------------------------------------------------------------------
// Final GEMM (operand-swapped): D[f][m] = sum_e Wft[f][e] * z[m][e]
// 64x64 tile, both operands bf16 via global_load_lds.
// Epilogue: x[m][f..f+4] = bf16(acc + bf + Qres). grid (8,128).
// ---------------------------------------------------------------------------
__global__ __launch_bounds__(256) void final_gemm_k(
    const bf16_t* __restrict__ zin, const bf16_t* __restrict__ Wft,
    const float* __restrict__ bfb, const float* __restrict__ Qres,
    bf16_t* __restrict__ x) {
  __shared__ bf16_t As[64 * 64];
  __shared__ bf16_t Bs[64 * 64];
  const int t = threadIdx.x;
  const int id = blockIdx.x + (blockIdx.y << 3);
  const int nid = (id & 7) * 128 + (id >> 3);
  const int n0 = (nid & 7) * 64;
  const int m0 = (nid >> 3) * 64;
  const int lane = t & 63, w = t >> 6;
  const int wn = w >> 1, wm = w & 1;
  const int rsel = lane & 15, grp = lane >> 4;
  const int wbase = (t & ~63);

  f32x4 acc[2][2];
#pragma unroll
  for (int ni = 0; ni < 2; ni++)
#pragma unroll
    for (int mi = 0; mi < 2; mi++) acc[ni][mi] = (f32x4){0.f, 0.f, 0.f, 0.f};

  for (int k0 = 0; k0 < Ee; k0 += 64) {
#pragma unroll
    for (int i = 0; i < 2; i++) {
      int slot = i * 256 + t;
      int row = slot >> 3;
      int g = (slot & 7) ^ (row & 7);
      GLOAD16(Wft + (size_t)(n0 + row) * Ee + k0 + g * 8,
              As + (size_t)(i * 256 + wbase) * 8);
      GLOAD16(zin + (size_t)(m0 + row) * Ee + k0 + g * 8,
              Bs + (size_t)(i * 256 + wbase) * 8);
    }
    __syncthreads();
#pragma unroll
    for (int kk = 0; kk < 2; kk++) {
      bf16x8 af[2], bff[2];
#pragma unroll
      for (int ni = 0; ni < 2; ni++) {
        int arow = wn * 32 + ni * 16 + rsel;
        int c = ((kk * 4 + grp) ^ (arow & 7)) * 8;
        af[ni] = *(const bf16x8*)&As[arow * 64 + c];
      }
#pragma unroll
      for (int mi = 0; mi < 2; mi++) {
        int brow = wm * 32 + mi * 16 + rsel;
        int c = ((kk * 4 + grp) ^ (brow & 7)) * 8;
        bff[mi] = *(const bf16x8*)&Bs[brow * 64 + c];
      }
#pragma unroll
      for (int ni = 0; ni < 2; ni++)
#pragma unroll
        for (int mi = 0; mi < 2; mi++)
          acc[ni][mi] = MFMA16(af[ni], bff[mi], acc[ni][mi]);
    }
    __syncthreads();
  }

#pragma unroll
  for (int ni = 0; ni < 2; ni++) {
    int nb = n0 + wn * 32 + ni * 16 + grp * 4;
    float4 b4 = *(const float4*)(bfb + nb);
#pragma unroll
    for (int mi = 0; mi < 2; mi++) {
      int m = m0 + wm * 32 + mi * 16 + rsel;
      float4 q4 = *(const float4*)(Qres + (size_t)m * Ee + nb);
      bf16x4 o;
      o[0] = f2bf(acc[ni][mi][0] + b4.x + q4.x);
      o[1] = f2bf(acc[ni][mi][1] + b4.y + q4.y);
      o[2] = f2bf(acc[ni][mi][2] + b4.z + q4.z);
      o[3] = f2bf(acc[ni][mi][3] + b4.w + q4.w);
      *(bf16x4*)(x + (size_t)m * Ee + nb) = o;
    }
  }
}

// ---------------------------------------------------------------------------
// Flash attention, 32x32 swapped-operand + in-block KV-split (unchanged
// structure from round 6; max3 tree + split exp-sum accumulators added).
// 8 waves = 4 q-subblocks x 2 KV-halves; grid (16, 32); KV tile = 64.
// ---------------------------------------------------------------------------
__global__ __launch_bounds__(512, 4) void attn_k(const bf16_t* __restrict__ qk,
                                                 const bf16_t* __restrict__ vtG,
                                                 bf16_t* __restrict__ zout) {
  const size_t HS = (size_t)Bb * Hh * Ss * DKk;
  __shared__ __align__(16) unsigned char smem_raw[2 * 34816];
  bf16_t (*Ks)[2][64][68] = reinterpret_cast<bf16_t (*)[2][64][68]>(smem_raw);
  bf16_t (*Vt)[2][64][68] = reinterpret_cast<bf16_t (*)[2][64][68]>(smem_raw + 34816);
  const int t = threadIdx.x, w = t >> 6, lane = t & 63;
  const int qsub = w >> 1, half = w & 1;
  const int ql = lane & 31, hi = lane >> 5;
  const int bh = blockIdx.y;
  const bf16_t* qp = qk + (size_t)bh * (Ss * DKk);
  const bf16_t* kp = qp + HS;
  const bf16_t* vt = vtG + (size_t)bh * ((size_t)DKk * Ss);
  const int qrow = blockIdx.x * 128 + qsub * 32 + ql;

  // Q B-fragments (hoisted): k-dim = dk, col = q
  bf16x8 qf0 = *(const bf16x8*)(qp + (size_t)qrow * DKk + 0 + hi * 8);
  bf16x8 qf1 = *(const bf16x8*)(qp + (size_t)qrow * DKk + 16 + hi * 8);
  bf16x8 qf2 = *(const bf16x8*)(qp + (size_t)qrow * DKk + 32 + hi * 8);
  bf16x8 qf3 = *(const bf16x8*)(qp + (size_t)qrow * DKk + 48 + hi * 8);

  // staging role within the half's 4 waves: sid in [0,256)
  const int sid = qsub * 64 + lane;
  const int srow = sid >> 2, sseg = sid & 3;
  const int koff0 = half * (Ss / 2);

  f32x16 ctx0, ctx1;
#pragma unroll
  for (int r = 0; r < 16; r++) { ctx0[r] = 0.f; ctx1[r] = 0.f; }
  float m_run = -1e30f, l_run = 0.f;

  // prologue: stage tile 0 of this half
  {
    const bf16_t* ksrc = kp + (size_t)(koff0 + srow) * DKk + sseg * 16;
    bf16x8 ka = ((const bf16x8*)ksrc)[0], kb = ((const bf16x8*)ksrc)[1];
    const bf16_t* vsrc = vt + (size_t)srow * Ss + koff0 + sseg * 16;
    bf16x8 va = ((const bf16x8*)vsrc)[0], vb = ((const bf16x8*)vsrc)[1];
    bf16_t* kd = &Ks[half][0][srow][sseg * 16];
    *(bf16x4*)(kd + 0) = LO4(ka); *(bf16x4*)(kd + 4) = HI4(ka);
    *(bf16x4*)(kd + 8) = LO4(kb); *(bf16x4*)(kd + 12) = HI4(kb);
    bf16_t* vd = &Vt[half][0][srow][sseg * 16];
    *(bf16x4*)(vd + 0) = LO4(va); *(bf16x4*)(vd + 4) = HI4(va);
    *(bf16x4*)(vd + 8) = LO4(vb); *(bf16x4*)(vd + 12) = HI4(vb);
  }
  __syncthreads();

  const int NT = (Ss / 2) / 64;  // 16 tiles per half
  bf16x8 pk0, pk1, pv0, pv1;
  for (int it = 0; it < NT; ++it) {
    const int cb = it & 1;
    if (it < NT - 1) {  // T14: issue next-tile global loads early
      const int k0 = koff0 + (it + 1) * 64;
      const bf16_t* ksrc = kp + (size_t)(k0 + srow) * DKk + sseg * 16;
      pk0 = ((const bf16x8*)ksrc)[0]; pk1 = ((const bf16x8*)ksrc)[1];
      const bf16_t* vsrc = vt + (size_t)srow * Ss + k0 + sseg * 16;
      pv0 = ((const bf16x8*)vsrc)[0]; pv1 = ((const bf16x8*)vsrc)[1];
    }

    // QK^T (swapped): st[key-group][16 regs], accumulate over 4 k-steps
    f32x16 st0, st1;
#pragma unroll
    for (int r = 0; r < 16; r++) { st0[r] = 0.f; st1[r] = 0.f; }
    __builtin_amdgcn_s_setprio(1);
#pragma unroll
    for (int s = 0; s < 4; s++) {
      bf16x4 a0 = *(const bf16x4*)&Ks[half][cb][ql][s * 16 + hi * 8];
      bf16x4 a1 = *(const bf16x4*)&Ks[half][cb][ql][s * 16 + hi * 8 + 4];
      bf16x8 af = __builtin_shufflevector(a0, a1, 0, 1, 2, 3, 4, 5, 6, 7);
      bf16x4 c0 = *(const bf16x4*)&Ks[half][cb][32 + ql][s * 16 + hi * 8];
      bf16x4 c1 = *(const bf16x4*)&Ks[half][cb][32 + ql][s * 16 + hi * 8 + 4];
      bf16x8 af2 = __builtin_shufflevector(c0, c1, 0, 1, 2, 3, 4, 5, 6, 7);
      bf16x8 qf = (s == 0) ? qf0 : ((s == 1) ? qf1 : ((s == 2) ? qf2 : qf3));
      st0 = MFMA32(af, qf, st0);
      st1 = MFMA32(af2, qf, st1);
    }
    __builtin_amdgcn_s_setprio(0);

    // online softmax (exp2 domain), defer-max THR=8; max3-tree reduce
    float h[16];
#pragma unroll
    for (int r = 0; r < 16; r++) h[r] = fmaxf(st0[r], st1[r]);
    float p0 = max3f(h[0], h[1], h[2]);
    float p1 = max3f(h[3], h[4], h[5]);
    float p2 = max3f(h[6], h[7], h[8]);
    float p3 = max3f(h[9], h[10], h[11]);
    float p4 = max3f(h[12], h[13], h[14]);
    float mx = fmaxf(max3f(p0, p1, p2), max3f(p3, p4, h[15]));
    mx = fmaxf(mx, __shfl_xor(mx, 32));
    if (__any(mx > m_run + 8.0f)) {
      float mn = fmaxf(m_run, mx);
      float sc = fast_exp2(m_run - mn);
      l_run *= sc;
#pragma unroll
      for (int r = 0; r < 16; r++) { ctx0[r] *= sc; ctx1[r] *= sc; }
      m_run = mn;
    }
    float psA = 0.f, psB = 0.f;
#pragma unroll
    for (int r = 0; r < 16; r++) { st0[r] = fast_exp2(st0[r] - m_run); psA += st0[r]; }
#pragma unroll
    for (int r = 0; r < 16; r++) { st1[r] = fast_exp2(st1[r] - m_run); psB += st1[r]; }
    float ps = psA + psB;
    ps += __shfl_xor(ps, 32);
    l_run += ps;

    // P -> bf16 B-fragments via cvt_pk + permlane32_swap (T12)
    union U { unsigned u[4]; bf16x8 v; };
    U F00, F01, F10, F11;
    {
      unsigned x0 = cvtpk(st0[0], st0[1]), y0 = cvtpk(st0[4], st0[5]); plswap(x0, y0);
      unsigned x1 = cvtpk(st0[2], st0[3]), y1 = cvtpk(st0[6], st0[7]); plswap(x1, y1);
      F00.u[0] = x0; F00.u[1] = x1; F00.u[2] = y0; F00.u[3] = y1;
      unsigned x2 = cvtpk(st0[8], st0[9]), y2 = cvtpk(st0[12], st0[13]); plswap(x2, y2);
      unsigned x3 = cvtpk(st0[10], st0[11]), y3 = cvtpk(st0[14], st0[15]); plswap(x3, y3);
      F01.u[0] = x2; F01.u[1] = x3; F01.u[2] = y2; F01.u[3] = y3;
      unsigned x4 = cvtpk(st1[0], st1[1]), y4 = cvtpk(st1[4], st1[5]); plswap(x4, y4);
      unsigned x5 = cvtpk(st1[2], st1[3]), y5 = cvtpk(st1[6], st1[7]); plswap(x5, y5);
      F10.u[0] = x4; F10.u[1] = x5; F10.u[2] = y4; F10.u[3] = y5;
      unsigned x6 = cvtpk(st1[8], st1[9]), y6 = cvtpk(st1[12], st1[13]); plswap(x6, y6);
      unsigned x7 = cvtpk(st1[10], st1[11]), y7 = cvtpk(st1[14], st1[15]); plswap(x7, y7);
      F11.u[0] = x6; F11.u[1] = x7; F11.u[2] = y6; F11.u[3] = y7;
    }

    // PV (swapped): ctxT[dk][q] += Vt-rows x P
    auto rdv = [&](int mtrow, int col) -> bf16x8 {
      bf16x4 lo4 = *(const bf16x4*)&Vt[half][cb][mtrow + ql][col + hi * 8];
      bf16x4 hi4 = *(const bf16x4*)&Vt[half][cb][mtrow + ql][col + hi * 8 + 4];
      return __builtin_shufflevector(lo4, hi4, 0, 1, 2, 3, 4, 5, 6, 7);
    };
    __builtin_amdgcn_s_setprio(1);
    ctx0 = MFMA32(rdv(0, 0), F00.v, ctx0);
    ctx0 = MFMA32(rdv(0, 16), F01.v, ctx0);
    ctx0 = MFMA32(rdv(0, 32), F10.v, ctx0);
    ctx0 = MFMA32(rdv(0, 48), F11.v, ctx0);
    ctx1 = MFMA32(rdv(32, 0), F00.v, ctx1);
    ctx1 = MFMA32(rdv(32, 16), F01.v, ctx1);
    ctx1 = MFMA32(rdv(32, 32), F10.v, ctx1);
    ctx1 = MFMA32(rdv(32, 48), F11.v, ctx1);
    __builtin_amdgcn_s_setprio(0);

    // write next tile to the other buffer
    if (it < NT - 1) {
      bf16_t* kd = &Ks[half][cb ^ 1][srow][sseg * 16];
      *(bf16x4*)(kd + 0) = LO4(pk0); *(bf16x4*)(kd + 4) = HI4(pk0);
      *(bf16x4*)(kd + 8) = LO4(pk1); *(bf16x4*)(kd + 12) = HI4(pk1);
      bf16_t* vd = &Vt[half][cb ^ 1][srow][sseg * 16];
      *(bf16x4*)(vd + 0) = LO4(pv0); *(bf16x4*)(vd + 4) = HI4(pv0);
      *(bf16x4*)(vd + 8) = LO4(pv1); *(bf16x4*)(vd + 12) = HI4(pv1);
    }
    __syncthreads();
  }

  // merge the two KV-halves via LDS (aliased over Ks/Vt; safe after barrier).
  // layout (floats): ctx [256][33], then m[256], l[256].
  float* mr = (float*)smem_raw;
  const int msl = qsub * 64 + lane;
  float* cslot = mr + msl * 33;
  float* mym = mr + 8448;
  float* myl = mr + 8704;
  if (half == 1) {
#pragma unroll
    for (int r = 0; r < 16; r++) { cslot[r] = ctx0[r]; cslot[16 + r] = ctx1[r]; }
    mym[msl] = m_run;
    myl[msl] = l_run;
  }
  __syncthreads();
  if (half == 0) {
    float m1 = mym[msl], l1 = myl[msl];
    float mt = fmaxf(m_run, m1);
    float f0 = fast_exp2(m_run - mt), f1 = fast_exp2(m1 - mt);
    float inv = 1.f / (l_run * f0 + l1 * f1);
    const int bI = bh >> 3, hh = bh & 7;
    bf16_t* zr = zout + ((size_t)bI * Ss + qrow) * Ee + hh * 64;
#pragma unroll
    for (int a = 0; a < 4; a++) {
      bf16x4 o0, o1;
#pragma unroll
      for (int b2 = 0; b2 < 4; b2++) {
        o0[b2] = f2bf((ctx0[a * 4 + b2] * f0 + cslot[a * 4 + b2] * f1) * inv);
        o1[b2] = f2bf((ctx1[a * 4 + b2] * f0 + cslot[16 + a * 4 + b2] * f1) * inv);
      }
      *(bf16x4*)(zr + a * 8 + hi * 4) = o0;
      *(bf16x4*)(zr + 32 + a * 8 + hi * 4) = o1;
    }
  }
}

// ---------------------------------------------------------------------------
// LayerNorm over E=512, bf16 input x. One wave per row. grid (2048), 256 thr.
// ---------------------------------------------------------------------------
__global__ __launch_bounds__(256) void ln_k(
    const bf16_t* __restrict__ x, const float* __restrict__ gamma,
    const float* __restrict__ beta, float* __restrict__ out) {
  int row = blockIdx.x * 4 + (threadIdx.x >> 6);
  int lane = threadIdx.x & 63;
  const bf16_t* xr = x + (size_t)row * Ee + lane * 8;
  bf16x8 xv = *(const bf16x8*)xr;
  float v[8];
#pragma unroll
  for (int i = 0; i < 8; i++) v[i] = (float)xv[i];
  float s = 0.f, ss = 0.f;
#pragma unroll
  for (int i = 0; i < 8; i++) { s += v[i]; ss += v[i] * v[i]; }
#pragma unroll
  for (int off = 32; off >= 1; off >>= 1) {
    s += __shfl_xor(s, off);
    ss += __shfl_xor(ss, off);
  }
  float mean = s * (1.f / 512.f);
  float var = ss * (1.f / 512.f) - mean * mean;
  float inv = rsqrtf(var + 1e-5f);
  float4 g0 = *(const float4*)(gamma + lane * 8);
  float4 g1 = *(const float4*)(gamma + lane * 8 + 4);
  float4 b0 = *(const float4*)(beta + lane * 8);
  float4 b1 = *(const float4*)(beta + lane * 8 + 4);
  float4 o0, o1;
  o0.x = (v[0] - mean) * inv * g0.x + b0.x;
  o0.y = (v[1] - mean) * inv * g0.y + b0.y;
  o0.z = (v[2] - mean) * inv * g0.z + b0.z;
  o0.w = (v[3] - mean) * inv * g0.w + b0.w;
  o1.x = (v[4] - mean) * inv * g1.x + b1.x;
  o1.y = (v[5] - mean) * inv * g1.y + b1.y;
  o1.z = (v[6] - mean) * inv * g1.z + b1.z;
  o1.w = (v[7] - mean) * inv * g1.w + b1.w;
  float* orow = out + (size_t)row * Ee;
  *(float4*)(orow + lane * 8) = o0;
  *(float4*)(orow + lane * 8 + 4) = o1;
}

// ---------------------------------------------------------------------------
extern "C" void kernel_launch(void* const* d_in, const int* in_sizes, int n_in,
                              void* d_out, int out_size, void* d_ws, size_t ws_size,
                              hipStream_t stream) {
  const float* Q = (const float*)d_in[0];
  const float* K = (const float*)d_in[1];
  const float* V = (const float*)d_in[2];
  const float* Wq = (const float*)d_in[3];
  const float* bq = (const float*)d_in[4];
  const float* Wk = (const float*)d_in[5];
  const float* bk = (const float*)d_in[6];
  const float* Wv = (const float*)d_in[7];
  const float* bv = (const float*)d_in[8];
  const float* Wf = (const float*)d_in[9];
  const float* bfb = (const float*)d_in[10];
  const float* gamma = (const float*)d_in[11];
  const float* beta = (const float*)d_in[12];
  float* out = (float*)d_out;

  // workspace layout (bf16 elements), total 44,040,192 B (no overlays):
  //   Wt   : 3*512*512  = 786432
  //   Wft  : 512*512    = 262144
  //   q    : 4,194,304     (projected q, [bh][s][dk], pre-scaled)
  //   k    : 4,194,304     (projected k, [bh][s][dk])
  //   vtG  : 4,194,304     (projected V^T, [bh][dk][s])
  //   z    : 4,194,304     (attn out, [b][s][e])
  //   x    : 4,194,304     (residual sum, bf16 [m][e])
  bf16_t* Wt = (bf16_t*)d_ws;
  bf16_t* Wft = Wt + 3 * Ee * Ee;
  bf16_t* qk = Wft + Ee * Ee;                       // q then k (adjacent)
  bf16_t* vtG = qk + (size_t)2 * Bb * Hh * Ss * DKk;
  bf16_t* z = vtG + (size_t)Bb * Hh * Ss * DKk;
  bf16_t* x = z + (size_t)Bb * Ss * Ee;

  pack_weights_k<<<dim3(8, 32), dim3(256), 0, stream>>>(Wq, Wk, Wv, Wf, Wt, Wft);
  proj_gemm_k<<<dim3(8, 128, 3), dim3(256), 0, stream>>>(Q, K, V, Wt, bq, bk, bv,
                                                         qk, vtG);
  attn_k<<<dim3(16, 32), dim3(512), 0, stream>>>(qk, vtG, z);
  final_gemm_k<<<dim3(8, 128), dim3(256), 0, stream>>>(z, Wft, bfb, Q, x);
  ln_k<<<dim3(2048), dim3(256), 0, stream>>>(x, gamma, beta, out);
}